// Round 12
// baseline (188.576 us; speedup 1.0000x reference)
//
#include <hip/hip_runtime.h>
#include <hip/hip_bf16.h>

typedef float  f32x4  __attribute__((ext_vector_type(4)));
typedef float  f32x8  __attribute__((ext_vector_type(8)));
typedef float  f32x16 __attribute__((ext_vector_type(16)));
typedef __bf16 bf16x8 __attribute__((ext_vector_type(8)));
typedef unsigned short u16x4 __attribute__((ext_vector_type(4)));
typedef unsigned short u16x8 __attribute__((ext_vector_type(8)));
typedef unsigned int   u32x4 __attribute__((ext_vector_type(4)));

#define QSCALE 0.18033688011112042f  // 0.125 * log2(e): folds 1/sqrt(64) and LOG2E

__device__ __forceinline__ unsigned short f2bf(float f) {
  __bf16 h = (__bf16)f;
  return __builtin_bit_cast(unsigned short, h);
}

__device__ __forceinline__ f32x4 mfma16(bf16x8 a, bf16x8 b, f32x4 c) {
  return __builtin_amdgcn_mfma_f32_16x16x32_bf16(a, b, c, 0, 0, 0);
}
__device__ __forceinline__ f32x16 mfma32(bf16x8 a, bf16x8 b, f32x16 c) {
  return __builtin_amdgcn_mfma_f32_32x32x16_bf16(a, b, c, 0, 0, 0);
}
__device__ __forceinline__ f32x16 zero16() {
  f32x16 v;
#pragma unroll
  for (int i = 0; i < 16; ++i) v[i] = 0.f;
  return v;
}

typedef const __attribute__((address_space(1))) void* gptr_t;
typedef __attribute__((address_space(3))) void* lptr_t;
__device__ __forceinline__ void gld16(const void* g, void* l) {
  __builtin_amdgcn_global_load_lds((gptr_t)g, (lptr_t)l, 16, 0, 0);
}

// ============ chunked "LDS-image" layout =====================================
// A GEMM operand [R][Kt] bf16 is stored as chunks of (128 rows x 32 k) = 8KB:
//   chunk(cb = rb*NT + kb), inside: elem offset = (lg*128 + r)*8 + e
//   where k = kb*32 + lg*8 + e  (lg 0..3, e 0..7), r = row&127.
// Staging a chunk into LDS is linear (tid*16B); fragment ds_read_b128 of
// 16 consecutive lanes then covers 256 contiguous bytes -> conflict-free.

// ---------------- conversion kernels ----------------
// x [8192][1024] f32 -> A1 chunks (NT=32), plain bf16.
__global__ __launch_bounds__(256) void prep_x(const float* __restrict__ x,
                                              unsigned short* __restrict__ A1) {
  const int mb = blockIdx.x >> 5;
  const int kB = blockIdx.x & 31;
#pragma unroll
  for (int ph = 0; ph < 2; ++ph) {
    int c = threadIdx.x + ph * 256;     // cell 0..511
    int lg = c >> 7, r = c & 127;
    f32x8 v = *(const f32x8*)(x + (size_t)(mb * 128 + r) * 1024 + kB * 32 + lg * 8);
    u16x8 h;
#pragma unroll
    for (int j = 0; j < 8; ++j) h[j] = f2bf(v[j]);
    *(u16x8*)(A1 + (size_t)(mb * 32 + kB) * 4096 + (size_t)c * 8) = h;
  }
}

// w [R][1024] f32 -> plain bf16 chunks (NT=32). Grid: (R/128) x 32.
__global__ __launch_bounds__(256) void prep_w(const float* __restrict__ w,
                                              unsigned short* __restrict__ o) {
  const int rb = blockIdx.x >> 5;
  const int kB = blockIdx.x & 31;
#pragma unroll
  for (int ph = 0; ph < 2; ++ph) {
    int c = threadIdx.x + ph * 256;
    int lg = c >> 7, r = c & 127;
    f32x8 v = *(const f32x8*)(w + (size_t)(rb * 128 + r) * 1024 + kB * 32 + lg * 8);
    u16x8 h;
#pragma unroll
    for (int j = 0; j < 8; ++j) h[j] = f2bf(v[j]);
    *(u16x8*)(o + (size_t)(rb * 32 + kB) * 4096 + (size_t)c * 8) = h;
  }
}

// ---------------- NT GEMM, ring-3, 128x128 tile, 4 waves ---------------------
// C[M][N] = A[M][K]*B[N][K]^T. BM=BN=128, BK=32, 256 thr (4 waves 2Mx2N),
// per-wave 64x64 (acc[4][4] -> 16 mfma16 per K-step per wave).
// LDS ring: 3 slots x 16KB = 48KB -> MINW blocks/CU. Counted vmcnt(4)+barrier.
// EPI=0 K/V attn-image slot order [hi][row][16B] (conflict-free attn reads).
template <int EPI, int MINW>
__global__ __launch_bounds__(256, MINW) void gemm_bt(
    const __bf16* __restrict__ A, const __bf16* __restrict__ B,
    const float* __restrict__ bias, int N, int nbx, int NT,
    unsigned short* __restrict__ q_out, unsigned short* __restrict__ k_out,
    unsigned short* __restrict__ v_out, float* __restrict__ f_out) {
  __shared__ __align__(16) char smem[3 * 16384];
  const int tid = threadIdx.x;
  const int lane = tid & 63;
  const int wave = tid >> 6;
  const int ln = lane & 15, lg = lane >> 4;
  const int wm = wave >> 1;  // 0..1 (row half)
  const int wn = wave & 1;   // 0..1 (col half)
  const int bm = blockIdx.x / nbx;
  const int bn = blockIdx.x % nbx;

  f32x4 acc[4][4];
#pragma unroll
  for (int i = 0; i < 4; ++i)
#pragma unroll
    for (int j = 0; j < 4; ++j) acc[i][j] = (f32x4){0.f, 0.f, 0.f, 0.f};

  // chunk-linear staging sources (chunk = 4096 elems = 8KB)
  const __bf16* Asrc = A + ((size_t)bm * NT) * 4096 + tid * 8;
  const __bf16* Bsrc = B + ((size_t)bn * NT) * 4096 + tid * 8;
  // conflict-free fragment read bases (bytes)
  const int aoff = lg * 2048 + (wm * 64 + ln) * 16;           // + mi*256
  const int boff = 8192 + lg * 2048 + (wn * 64 + ln) * 16;    // + ni*256

#define STAGE(slot_, tf_)                                                      \
  do {                                                                         \
    char* d_ = smem + (slot_) * 16384;                                         \
    const __bf16* a_ = Asrc + (size_t)(tf_) * 4096;                            \
    const __bf16* b_ = Bsrc + (size_t)(tf_) * 4096;                            \
    gld16(a_, d_ + tid * 16);                                                  \
    gld16(a_ + 2048, d_ + 4096 + tid * 16);                                    \
    gld16(b_, d_ + 8192 + tid * 16);                                           \
    gld16(b_ + 2048, d_ + 12288 + tid * 16);                                   \
  } while (0)

#define KBODY(t_, scur_, snxt_)                                                \
  do {                                                                         \
    int tf_ = ((t_) + 2 < NT) ? (t_) + 2 : NT - 1;                             \
    STAGE(snxt_, tf_);                                                         \
    const char* ab_ = smem + (scur_) * 16384;                                  \
    bf16x8 af_[4], bq_[4];                                                     \
    _Pragma("unroll") for (int mi = 0; mi < 4; ++mi)                           \
        af_[mi] = *(const bf16x8*)(ab_ + aoff + mi * 256);                     \
    _Pragma("unroll") for (int ni = 0; ni < 4; ++ni)                           \
        bq_[ni] = *(const bf16x8*)(ab_ + boff + ni * 256);                     \
    __builtin_amdgcn_s_setprio(1);                                             \
    _Pragma("unroll") for (int mi = 0; mi < 4; ++mi)                           \
        _Pragma("unroll") for (int ni = 0; ni < 4; ++ni)                       \
            acc[mi][ni] = mfma16(af_[mi], bq_[ni], acc[mi][ni]);               \
    __builtin_amdgcn_s_setprio(0);                                             \
    asm volatile("s_waitcnt vmcnt(4)\n\ts_barrier" ::: "memory");              \
  } while (0)

  // prologue: tiles 0,1 -> slots 0,1; wait tile 0 complete (<=4 outstanding)
  STAGE(0, 0);
  STAGE(1, 1);
  asm volatile("s_waitcnt vmcnt(4)\n\ts_barrier" ::: "memory");

  for (int t = 0; t < NT; t += 3) {
    KBODY(t, 0, 2);
    if (t + 1 < NT) KBODY(t + 1, 1, 0);
    if (t + 2 < NT) KBODY(t + 2, 2, 1);
  }
  // drain residual staging loads before endpgm
  asm volatile("s_waitcnt vmcnt(0)" ::: "memory");
#undef KBODY
#undef STAGE

  // epilogue
#pragma unroll
  for (int mi = 0; mi < 4; ++mi) {
#pragma unroll
    for (int ni = 0; ni < 4; ++ni) {
      int n = bn * 128 + wn * 64 + ni * 16 + ln;
      float bv = bias[n];
#pragma unroll
      for (int j = 0; j < 4; ++j) {
        int m = bm * 128 + wm * 64 + mi * 16 + lg * 4 + j;
        float val = acc[mi][ni][j] + bv;
        if constexpr (EPI == 0) {
          int h = n / 192;
          int r3 = n - h * 192;
          int b = m >> 11;
          int t = m & 2047;
          size_t base = (size_t)(b * 16 + h) << 17;  // *131072 elems per bh
          if (r3 < 64) {
            q_out[base + ((size_t)t << 6) + r3] = f2bf(val * QSCALE);
          } else if (r3 < 128) {
            // K image: region (t2*4+ks)*512, in-region h8*256 + (kv&31)*8 + e
            int d = r3 - 64;
            size_t off = base + (size_t)(t >> 6) * 4096 +
                         (size_t)((((t >> 5) & 1) << 2) + (d >> 4)) * 512 +
                         ((d >> 3) & 1) * 256 + (t & 31) * 8 + (d & 7);
            k_out[off] = f2bf(val);
          } else {
            // V^T image: region (di*4 + kblock)*512, in-region h8*256 + (c&31)*8 + e
            int c = r3 - 128;
            size_t off = base + (size_t)(t >> 6) * 4096 +
                         (size_t)(((c >> 5) << 2) + ((t >> 4) & 3)) * 512 +
                         ((t >> 3) & 1) * 256 + (c & 31) * 8 + (t & 7);
            v_out[off] = f2bf(val);
          }
        } else {
          f_out[(size_t)m * N + n] = val;
        }
      }
    }
  }
}

// ---------------- flash attention, 4 waves x 64 q-rows (2 groups) ------------
// 256 thr, grid 512 = 2 blocks/CU (2 waves/SIMD). Each wave owns TWO 32-q
// groups: K/V fragments are read from LDS ONCE and feed both groups' MFMA
// chains (16 ds_read serve 40 mfma32 -> LDS-read per unit work halved; all
// waves of a block read identical K/V, so fewer waves = less LDS traffic).
// Ring-3 LDS, counted vmcnt(4). Softmax shift-invariant (no max tracking);
// denominator on the MFMA pipe (all-ones A-fragment). permlane32_swap builds
// the PV B-operand; odd waves reverse subtile order; setprio around MFMA.
__global__ __launch_bounds__(256, 2) void attn2(
    const __bf16* __restrict__ Q, const __bf16* __restrict__ Kg,
    const __bf16* __restrict__ Vg, unsigned short* __restrict__ res) {
  __shared__ __align__(16) char smem[3 * 16384];  // ring-3: K 8KB | V 8KB each
  const int tid = threadIdx.x;
  const int lane = tid & 63;
  const int wq = tid >> 6;           // 0..3
  const int l31 = lane & 31;
  const int hi = lane >> 5;
  const int bh = blockIdx.x & 63;    // stride-64 bids share bh -> same XCD
  const int q0 = (blockIdx.x >> 6) << 8;  // 256 q rows per block
  const size_t bh_elem = (size_t)bh << 17;

  const __bf16* Kbh = Kg + bh_elem;
  const __bf16* Vbh = Vg + bh_elem;

  bf16x8 qf0[4], qf1[4];
  {
    const __bf16* qr0 = Q + bh_elem + ((size_t)(q0 + wq * 64 + l31) << 6) + hi * 8;
    const __bf16* qr1 = qr0 + (32 << 6);
#pragma unroll
    for (int ks = 0; ks < 4; ++ks) {
      qf0[ks] = *(const bf16x8*)(qr0 + ks * 16);
      qf1[ks] = *(const bf16x8*)(qr1 + ks * 16);
    }
  }
  // all-ones A-fragment (bf16 1.0) for the denominator MFMA
  const u16x8 one8 = {0x3F80, 0x3F80, 0x3F80, 0x3F80,
                      0x3F80, 0x3F80, 0x3F80, 0x3F80};
  const bf16x8 ones = __builtin_bit_cast(bf16x8, one8);

  const f32x16 fz = zero16();  // persistent zero C-operand
  f32x16 oA0 = zero16(), oA1 = zero16(), lA = zero16();  // group 0
  f32x16 oB0 = zero16(), oB1 = zero16(), lB = zero16();  // group 1

#define AST(slot_, t_)                                                         \
  do {                                                                         \
    char* sb_ = smem + (slot_) * 16384;                                        \
    _Pragma("unroll") for (int it_ = 0; it_ < 2; ++it_) {                      \
      int idx_ = tid + it_ * 256;                                              \
      gld16(Kbh + (size_t)(t_) * 4096 + idx_ * 8, sb_ + idx_ * 16);            \
      gld16(Vbh + (size_t)(t_) * 4096 + idx_ * 8, sb_ + 8192 + idx_ * 16);     \
    }                                                                          \
  } while (0)

  // prologue: tiles 0,1 -> slots 0,1; wait tile 0 (4 outstanding = tile 1)
  AST(0, 0);
  AST(1, 1);
  asm volatile("s_waitcnt vmcnt(4)\n\ts_barrier" ::: "memory");

  const int t2rev = wq & 1;  // de-phase: odd waves reverse subtile order
  int sc = 0;                // slot of current tile
  for (int tile = 0; tile < 32; ++tile) {
    int tf = (tile + 2 < 32) ? tile + 2 : 31;   // clamped redundant tail stage
    int sn = sc + 2; if (sn >= 3) sn -= 3;      // slot for tile+2
    AST(sn, tf);

    const char* kbase = smem + sc * 16384;
    const char* vbase = kbase + 8192;
    const int loff = hi * 512 + l31 * 16;  // contiguous per half-wave

#pragma unroll
    for (int tt = 0; tt < 2; ++tt) {
      const int t2 = tt ^ t2rev;
      f32x16 s0, s1;
      __builtin_amdgcn_s_setprio(1);
      {
        bf16x8 kf = *(const bf16x8*)(kbase + (t2 * 4) * 1024 + loff);
        s0 = mfma32(kf, qf0[0], fz);
        s1 = mfma32(kf, qf1[0], fz);
      }
#pragma unroll
      for (int ks = 1; ks < 4; ++ks) {
        bf16x8 kf = *(const bf16x8*)(kbase + (t2 * 4 + ks) * 1024 + loff);
        s0 = mfma32(kf, qf0[ks], s0);
        s1 = mfma32(kf, qf1[ks], s1);
      }
      __builtin_amdgcn_s_setprio(0);
      unsigned int pkA[8], pkB[8];
      {
        float p[16];
#pragma unroll
        for (int r = 0; r < 16; ++r) p[r] = __builtin_amdgcn_exp2f(s0[r]);
#pragma unroll
        for (int i = 0; i < 8; ++i)
          pkA[i] = ((unsigned int)f2bf(p[2 * i + 1]) << 16) | f2bf(p[2 * i]);
      }
      {
        float p[16];
#pragma unroll
        for (int r = 0; r < 16; ++r) p[r] = __builtin_amdgcn_exp2f(s1[r]);
#pragma unroll
        for (int i = 0; i < 8; ++i)
          pkB[i] = ((unsigned int)f2bf(p[2 * i + 1]) << 16) | f2bf(p[2 * i]);
      }
      // v_permlane32_swap: x' = {x.lo, y.lo}, y' = {x.hi, y.hi}.
      asm volatile("v_permlane32_swap_b32 %0, %1" : "+v"(pkA[0]), "+v"(pkA[2]));
      asm volatile("v_permlane32_swap_b32 %0, %1" : "+v"(pkA[1]), "+v"(pkA[3]));
      asm volatile("v_permlane32_swap_b32 %0, %1" : "+v"(pkA[4]), "+v"(pkA[6]));
      asm volatile("v_permlane32_swap_b32 %0, %1" : "+v"(pkA[5]), "+v"(pkA[7]));
      asm volatile("v_permlane32_swap_b32 %0, %1" : "+v"(pkB[0]), "+v"(pkB[2]));
      asm volatile("v_permlane32_swap_b32 %0, %1" : "+v"(pkB[1]), "+v"(pkB[3]));
      asm volatile("v_permlane32_swap_b32 %0, %1" : "+v"(pkB[4]), "+v"(pkB[6]));
      asm volatile("v_permlane32_swap_b32 %0, %1" : "+v"(pkB[5]), "+v"(pkB[7]));
      __builtin_amdgcn_s_setprio(1);
#pragma unroll
      for (int ks2 = 0; ks2 < 2; ++ks2) {
        u32x4 bwA = {pkA[ks2 * 4 + 0], pkA[ks2 * 4 + 1],
                     pkA[ks2 * 4 + 2], pkA[ks2 * 4 + 3]};
        u32x4 bwB = {pkB[ks2 * 4 + 0], pkB[ks2 * 4 + 1],
                     pkB[ks2 * 4 + 2], pkB[ks2 * 4 + 3]};
        bf16x8 pbA = __builtin_bit_cast(bf16x8, bwA);
        bf16x8 pbB = __builtin_bit_cast(bf16x8, bwB);
        int kb2 = t2 * 2 + ks2;
        bf16x8 v0 = *(const bf16x8*)(vbase + (kb2) * 1024 + loff);
        bf16x8 v1 = *(const bf16x8*)(vbase + (4 + kb2) * 1024 + loff);
        lA  = mfma32(ones, pbA, lA);
        oA0 = mfma32(v0, pbA, oA0);
        oA1 = mfma32(v1, pbA, oA1);
        lB  = mfma32(ones, pbB, lB);
        oB0 = mfma32(v0, pbB, oB0);
        oB1 = mfma32(v1, pbB, oB1);
      }
      __builtin_amdgcn_s_setprio(0);
    }
    asm volatile("s_waitcnt vmcnt(4)\n\ts_barrier" ::: "memory");
    sc = (sc + 1 == 3) ? 0 : sc + 1;
  }
  // drain residual staging loads
  asm volatile("s_waitcnt vmcnt(0)" ::: "memory");
#undef AST

  // epilogue: write res in chunked layout. trow = q0 + wq*64 + g*32 + l31.
  const int b = bh >> 4, h = bh & 15;
#pragma unroll
  for (int g = 0; g < 2; ++g) {
    float rl = __builtin_amdgcn_rcpf(g ? lB[0] : lA[0]);
    const int rloc = wq * 64 + g * 32 + l31;             // 0..255
    const int mb = b * 16 + (blockIdx.x >> 6) * 2 + (rloc >> 7);
    const int r = rloc & 127;
    unsigned short* c0 = res + (size_t)(mb * 32 + 2 * h) * 4096 + r * 8 + hi * 4;
#pragma unroll
    for (int gg = 0; gg < 4; ++gg) {
      u16x4 st0, st1;
#pragma unroll
      for (int rr = 0; rr < 4; ++rr) {
        st0[rr] = f2bf((g ? oB0[gg * 4 + rr] : oA0[gg * 4 + rr]) * rl);
        st1[rr] = f2bf((g ? oB1[gg * 4 + rr] : oA1[gg * 4 + rr]) * rl);
      }
      *(u16x4*)(c0 + gg * 1024) = st0;            // kb = 2h,  lg = gg
      *(u16x4*)(c0 + 4096 + gg * 1024) = st1;     // kb = 2h+1, lg = gg
    }
  }
}

// ---------------- launch -----------------------------------------------------
extern "C" void kernel_launch(void* const* d_in, const int* in_sizes, int n_in,
                              void* d_out, int out_size, void* d_ws, size_t ws_size,
                              hipStream_t stream) {
  const float* x    = (const float*)d_in[0];
  const float* Wqkv = (const float*)d_in[1];
  const float* bqkv = (const float*)d_in[2];
  const float* Wout = (const float*)d_in[3];
  const float* bout = (const float*)d_in[4];
  float* out = (float*)d_out;
  char* ws = (char*)d_ws;

  unsigned short* A1 = (unsigned short*)(ws);              // chunks 64x32x8KB = 16.8MB
  unsigned short* B1 = (unsigned short*)(ws + 50331648);   // chunks 24x32x8KB = 6.3MB
  unsigned short* Qb = (unsigned short*)(ws + 69206016);   // [64][2048][64]
  unsigned short* Kb = (unsigned short*)(ws + 85983232);   // attn image
  unsigned short* Vb = (unsigned short*)(ws + 102760448);  // attn image
  unsigned short* Rb = (unsigned short*)(ws + 119537664);  // chunks 64x32x8KB
  unsigned short* Wo = (unsigned short*)(ws + 136314880);  // chunks 8x32x8KB

  prep_x<<<64 * 32, 256, 0, stream>>>(x, A1);
  prep_w<<<24 * 32, 256, 0, stream>>>(Wqkv, B1);
  prep_w<<<8 * 32, 256, 0, stream>>>(Wout, Wo);

  // QKV GEMM, plain bf16 (K=1024): 128^2 tiles, grid 1536 @ 3 blk/CU = 2 rounds
  gemm_bt<0, 3><<<64 * 24, 256, 0, stream>>>((const __bf16*)A1, (const __bf16*)B1,
                                             bqkv, 3072, 24, 32,
                                             Qb, Kb, Vb, nullptr);

  attn2<<<512, 256, 0, stream>>>((const __bf16*)Qb, (const __bf16*)Kb,
                                 (const __bf16*)Vb, Rb);

  // out = res . W_out^T + b_out: 128^2 tiles, grid 512 @ 2 blk/CU = 1 round
  gemm_bt<1, 2><<<64 * 8, 256, 0, stream>>>((const __bf16*)Rb, (const __bf16*)Wo,
                                            bout, 1024, 8, 32,
                                            nullptr, nullptr, nullptr, out);
}